// Round 2
// baseline (3892.690 us; speedup 1.0000x reference)
//
#include <hip/hip_runtime.h>
#include <hip/hip_bf16.h>

typedef __hip_bfloat16 bf16;
typedef __attribute__((ext_vector_type(8))) short short8;
typedef __attribute__((ext_vector_type(4))) float float4v;

#define BSZ 32
#define TT  128
#define IC  16
#define NDIM 512
#define WS_NEED ((size_t)4 * IC * NDIM * NDIM * 2)   // 33.55 MB bf16 packed weights
#define SMEM_BYTES 163840                            // 128 KiB weights + 32 KiB h

// per-channel arrival counters, padded to 256 B so each channel's 16 spinners
// contend on their own line. Zeroed by pack_w (stream-ordered before es_persist).
__device__ __attribute__((aligned(256))) unsigned g_ctr[IC * 64];

__device__ __forceinline__ float sigf(float v) { return 1.0f / (1.0f + expf(-v)); }
__device__ __forceinline__ unsigned f2bfb(float f) {
    bf16 h = __float2bfloat16(f);
    return (unsigned)*reinterpret_cast<unsigned short*>(&h);
}
// LDS h swizzle: chunk c (16B of 8 bf16) of row r lives at byte
// r*1024 + ((c>>3)<<7) | (((c ^ r ^ (c>>3)) & 7) << 4)
// -> staging writes AND A-fragment reads are bank-conflict-free at the b128 floor.
__device__ __forceinline__ int swzb(int row, int c) {
    return ((c >> 3) << 7) | ((((c ^ row) ^ (c >> 3)) & 7) << 4);
}

// ---------------- one-time weight pack: fp32 W -> bf16 MFMA B-fragments ----
// uint4 index = ((blk*16 + kstep)*64 + lane), blk = (g*IC + i)*32 + nt16
// lane frag elems j=0..7:  W_g[i][ kstep*32 + (lane>>4)*8 + j ][ nt16*16 + (lane&15) ]
__global__ void pack_w(const float* __restrict__ Wj, const float* __restrict__ Wi,
                       const float* __restrict__ Wf, const float* __restrict__ Wo,
                       uint4* __restrict__ wpk)
{
    __shared__ float tile[NDIM][17];
    const int blk  = blockIdx.x;
    if (blk == 0) {   // reset barrier counters (visible via end-of-kernel release)
        for (int k = threadIdx.x; k < IC * 64; k += 256) g_ctr[k] = 0u;
    }
    const int nt16 = blk & 31;
    const int i    = (blk >> 5) & 15;
    const int g    = blk >> 9;
    const float* W = (g == 0) ? Wj : (g == 1) ? Wi : (g == 2) ? Wf : Wo;
    const float* base = W + (size_t)i * NDIM * NDIM + nt16 * 16;
    const int tid = threadIdx.x;

    #pragma unroll
    for (int r = 0; r < 2; r++) {
        int n = tid + r * 256;
        const float4* p = (const float4*)(base + (size_t)n * NDIM);
        float4 v0 = p[0], v1 = p[1], v2 = p[2], v3 = p[3];
        float* d = &tile[n][0];
        d[0]=v0.x; d[1]=v0.y; d[2]=v0.z; d[3]=v0.w;
        d[4]=v1.x; d[5]=v1.y; d[6]=v1.z; d[7]=v1.w;
        d[8]=v2.x; d[9]=v2.y; d[10]=v2.z; d[11]=v2.w;
        d[12]=v3.x; d[13]=v3.y; d[14]=v3.z; d[15]=v3.w;
    }
    __syncthreads();
    #pragma unroll
    for (int p = 0; p < 4; p++) {
        int f = p * 256 + tid;
        int kstep = f >> 6, L = f & 63;
        int quad = L >> 4, col = L & 15;
        int nr = kstep * 32 + quad * 8;
        unsigned u[4];
        #pragma unroll
        for (int w = 0; w < 4; w++) {
            unsigned lo = f2bfb(tile[nr + 2 * w][col]);
            unsigned hi = f2bfb(tile[nr + 2 * w + 1][col]);
            u[w] = lo | (hi << 16);
        }
        wpk[(size_t)blk * 1024 + (size_t)kstep * 64 + L] = make_uint4(u[0], u[1], u[2], u[3]);
    }
}

// ---------------- persistent all-timesteps kernel ----------------
// grid (IC, 16): block = (channel i, 32-col tile kt). 1 block/CU (LDS-capped), 256 blocks.
// Weights resident in LDS for all 128 steps. Cross-block h exchange is done with
// device-coherent (agent-scope relaxed atomic) stores/loads -> NO wbl2/inv cache ops
// in the steady-state loop; L2 stays warm. out is time-indexed so no aliasing.
__launch_bounds__(256, 1)
__global__ void es_persist(
    const float* __restrict__ x,
    const float* __restrict__ Uj, const float* __restrict__ Ui,
    const float* __restrict__ Uf, const float* __restrict__ Uo,
    const uint4* __restrict__ wpk,
    const float* __restrict__ bj, const float* __restrict__ bi,
    const float* __restrict__ bfp, const float* __restrict__ bo,
    float* __restrict__ out)
{
    extern __shared__ unsigned char smem[];
    uint4* w_lds = (uint4*)smem;               // 128 KiB: [ntl][gate][ks][lane] 16B frags
    unsigned char* h_base = smem + 131072;     // 32 KiB: row b at b*1024 B, swzb chunks

    const int i   = blockIdx.x;        // channel
    const int kt  = blockIdx.y;        // 32-col tile
    const int tid = threadIdx.x;
    const int wid = tid >> 6, L = tid & 63;
    const int quad = L >> 4, c15 = L & 15;
    const int ntl  = wid & 1;                  // local 16-col tile
    const int nt16 = kt * 2 + ntl;
    const int Mh   = (wid >> 1) * 16;          // batch half

    float* hfin = out + (size_t)BSZ * TT * IC * NDIM;
    float* cfin = hfin + (size_t)BSZ * IC * NDIM;

    // ---- prologue: this block's packed weights -> LDS (once)
    #pragma unroll
    for (int f = 0; f < 32; f++) {
        int d = f * 256 + tid;
        int lntl = d >> 12, g = (d >> 10) & 3, ks = (d >> 6) & 15, l = d & 63;
        w_lds[d] = wpk[((size_t)(g * IC + i) * 32 + (kt * 2 + lntl)) * 1024 + (size_t)ks * 64 + l];
    }

    // ---- hoist loop-invariant per-lane scalars into registers
    const int n = nt16 * 16 + c15;
    const size_t un = (size_t)i * NDIM + n;
    const float u0 = Uj[un], u1 = Ui[un], u2 = Uf[un], u3 = Uo[un];
    const float c0 = bj[un], c1 = bi[un], c2 = bfp[un], c3 = bo[un];
    const float a_out = 0.990049834f;          // exp(-0.01)

    float cc[4] = {0.f, 0.f, 0.f, 0.f};        // c-state lives in registers across all steps

    // staging mapping: thread (sb, sn0) gathers 64 consecutive h cols of batch row sb
    const int sb = tid >> 3, sn0 = (tid & 7) * 64;

    __syncthreads();

    #pragma unroll 1
    for (int t = 0; t < TT; t++) {
        float4v acc0 = {0,0,0,0}, acc1 = {0,0,0,0}, acc2 = {0,0,0,0}, acc3 = {0,0,0,0};

        // x loads depend on no other block: issue before the wait so latency hides under it
        float xv[4];
        #pragma unroll
        for (int r = 0; r < 4; r++)
            xv[r] = x[(size_t)((Mh + quad * 4 + r) * TT + t) * IC + i];

        if (t > 0) {
            // ---- wait for all 16 blocks of channel i to have published h(t-1)
            if (tid == 0) {
                const unsigned target = 16u * (unsigned)t;
                long spins = 0;
                while (__hip_atomic_load(&g_ctr[i << 6], __ATOMIC_RELAXED, __HIP_MEMORY_SCOPE_AGENT) < target) {
                    __builtin_amdgcn_s_sleep(1);
                    if (++spins > 40000000L) break;   // fail loud (bad data), never hang
                }
            }
            __syncthreads();

            // ---- gather h[:, t-1, i, :] with device-coherent loads (bypass stale L1/L2),
            //      convert to bf16, write swizzled into LDS
            {
                float* hsrc = out + ((size_t)(sb * TT + (t - 1)) * IC + i) * NDIM + sn0;
                float hv[64];
                #pragma unroll
                for (int k = 0; k < 64; k++)
                    hv[k] = __hip_atomic_load(hsrc + k, __ATOMIC_RELAXED, __HIP_MEMORY_SCOPE_AGENT);
                #pragma unroll
                for (int q = 0; q < 8; q++) {
                    unsigned v0 = f2bfb(hv[q * 8 + 0]) | (f2bfb(hv[q * 8 + 1]) << 16);
                    unsigned v1 = f2bfb(hv[q * 8 + 2]) | (f2bfb(hv[q * 8 + 3]) << 16);
                    unsigned v2 = f2bfb(hv[q * 8 + 4]) | (f2bfb(hv[q * 8 + 5]) << 16);
                    unsigned v3 = f2bfb(hv[q * 8 + 6]) | (f2bfb(hv[q * 8 + 7]) << 16);
                    int cw = (sn0 >> 3) + q;
                    *(uint4*)(h_base + sb * 1024 + swzb(sb, cw)) = make_uint4(v0, v1, v2, v3);
                }
            }
            __syncthreads();

            // ---- MFMA: A from swizzled h LDS, B from resident weight LDS
            const int arow = Mh + c15;
            const unsigned char* aptr = h_base + arow * 1024;
            const uint4* wb = w_lds + ntl * 4096 + L;     // gate stride 1024 uint4
            #pragma unroll 4
            for (int ks = 0; ks < 16; ks++) {
                short8 a  = *(const short8*)(aptr + swzb(arow, ks * 4 + quad));
                short8 b0 = *(const short8*)(wb + ks * 64);
                short8 b1 = *(const short8*)(wb + 1024 + ks * 64);
                short8 b2 = *(const short8*)(wb + 2048 + ks * 64);
                short8 b3 = *(const short8*)(wb + 3072 + ks * 64);
                acc0 = __builtin_amdgcn_mfma_f32_16x16x32_bf16(a, b0, acc0, 0, 0, 0);
                acc1 = __builtin_amdgcn_mfma_f32_16x16x32_bf16(a, b1, acc1, 0, 0, 0);
                acc2 = __builtin_amdgcn_mfma_f32_16x16x32_bf16(a, b2, acc2, 0, 0, 0);
                acc3 = __builtin_amdgcn_mfma_f32_16x16x32_bf16(a, b3, acc3, 0, 0, 0);
            }
        }

        // ---- epilogue (all 4 gates resident in this wave's acc regs)
        #pragma unroll
        for (int r = 0; r < 4; r++) {
            const int b = Mh + quad * 4 + r;    // C-layout row

            float jg = tanhf(acc0[r] + c0 + xv[r] * u0);
            float ig = sigf (acc1[r] + c1 + xv[r] * u1);
            float fg = sigf (acc2[r] + c2 + xv[r] * u2);
            float og = sigf (acc3[r] + c3 + xv[r] * u3);

            float alpha_m = expf(-7.8125e-5f * jg);
            float ro      = expf(-1.5625e-4f * ig);
            float b_ad    = ro * 0.1f + (1.0f - ro) * ig;
            float Bth     = 0.04f + 1.8f * b_ad;

            float hprev = 0.0f;
            if (t > 0)   // coeff (1-alpha)~7.8e-5: bf16 is free (same as prior verified kernel)
                hprev = __bfloat162float(*(const bf16*)(h_base + b * 1024 + swzb(b, n >> 3) + (n & 7) * 2));

            float mem   = jg * alpha_m + (1.0f - alpha_m) * hprev - Bth * ig * 0.01f;
            float spike = (mem - Bth) > 0.0f ? 1.0f : 0.0f;
            float mem_o = mem * a_out + (1.0f - a_out) * spike + 0.08f;

            float cn = cc[r] * fg + ig * spike * mem_o;
            float hn = og * tanhf(cn);
            cc[r] = cn;

            // device-coherent (write-through) store: lands at the mall, no dirty L2 line
            __hip_atomic_store(out + ((size_t)(b * TT + t) * IC + i) * NDIM + n, hn,
                               __ATOMIC_RELAXED, __HIP_MEMORY_SCOPE_AGENT);
            if (t == TT - 1) {
                size_t sidx = ((size_t)b * IC + i) * NDIM + n;
                cfin[sidx] = cn;
                hfin[sidx] = hn;
            }
        }

        // ---- publish h(t): drain this thread's coherent stores, join, bump counter.
        // All payload stores are agent-scope atomics (already at the coherent point once
        // vmcnt retires) -> relaxed add suffices, no wbl2/inv needed.
        if (t < TT - 1) {
            asm volatile("s_waitcnt vmcnt(0)" ::: "memory");
            __syncthreads();
            if (tid == 0)
                __hip_atomic_fetch_add(&g_ctr[i << 6], 1u, __ATOMIC_RELAXED, __HIP_MEMORY_SCOPE_AGENT);
        }
    }
}

// ---------------- fallback (proven R5 path, used only if ws too small) ----
#define KT 32
#define NC 64
__launch_bounds__(256)
__global__ void step_kernel_valu(int t,
    const float* __restrict__ x,
    const float* __restrict__ Uj, const float* __restrict__ Ui, const float* __restrict__ Uf, const float* __restrict__ Uo,
    const float* __restrict__ Wj, const float* __restrict__ Wi, const float* __restrict__ Wf, const float* __restrict__ Wo,
    const float* __restrict__ bj, const float* __restrict__ bi, const float* __restrict__ bfp, const float* __restrict__ bo,
    float* __restrict__ out)
{
    __shared__ float w_lds[NC][KT * 4 + 4];
    __shared__ float h_lds[NC][BSZ + 4];
    const int i = blockIdx.x, k0 = blockIdx.y * KT, tid = threadIdx.x;
    const int kl = tid & 31, bg = tid >> 5, kg = k0 + kl;
    float* hfin = out + (size_t)BSZ * TT * IC * NDIM;
    float* cfin = hfin + (size_t)BSZ * IC * NDIM;
    float acc[4][4];
    {
        size_t uidx = (size_t)i * NDIM + kg;
        float u0 = Uj[uidx], u1 = Ui[uidx], u2 = Uf[uidx], u3 = Uo[uidx];
        float c0 = bj[uidx], c1 = bi[uidx], c2 = bfp[uidx], c3 = bo[uidx];
        #pragma unroll
        for (int j = 0; j < 4; j++) {
            int b = bg * 4 + j;
            float xv = x[(size_t)(b * TT + t) * IC + i];
            acc[0][j] = c0 + xv * u0; acc[1][j] = c1 + xv * u1;
            acc[2][j] = c2 + xv * u2; acc[3][j] = c3 + xv * u3;
        }
    }
    if (t > 0) {
        for (int n0 = 0; n0 < NDIM; n0 += NC) {
            __syncthreads();
            {
                int g = tid >> 6, nn = tid & 63;
                const float* Wp = (g == 0) ? Wj : (g == 1) ? Wi : (g == 2) ? Wf : Wo;
                const float4* p = (const float4*)(Wp + ((size_t)i * NDIM + (size_t)(n0 + nn)) * NDIM + k0);
                #pragma unroll
                for (int q = 0; q < 8; q++) {
                    float4 v = p[q];
                    w_lds[nn][(q * 4 + 0) * 4 + g] = v.x; w_lds[nn][(q * 4 + 1) * 4 + g] = v.y;
                    w_lds[nn][(q * 4 + 2) * 4 + g] = v.z; w_lds[nn][(q * 4 + 3) * 4 + g] = v.w;
                }
            }
            {
                int b = tid >> 3, nb = (tid & 7) * 8;
                const float4* ph = (const float4*)(out + ((size_t)(b * TT + (t - 1)) * IC + i) * NDIM + n0 + nb);
                float4 h0 = ph[0], h1 = ph[1];
                h_lds[nb + 0][b] = h0.x; h_lds[nb + 1][b] = h0.y; h_lds[nb + 2][b] = h0.z; h_lds[nb + 3][b] = h0.w;
                h_lds[nb + 4][b] = h1.x; h_lds[nb + 5][b] = h1.y; h_lds[nb + 6][b] = h1.z; h_lds[nb + 7][b] = h1.w;
            }
            __syncthreads();
            #pragma unroll 8
            for (int nn = 0; nn < NC; nn++) {
                float4 wv = *(const float4*)&w_lds[nn][kl * 4];
                float4 hv = *(const float4*)&h_lds[nn][bg * 4];
                acc[0][0] += hv.x * wv.x; acc[1][0] += hv.x * wv.y; acc[2][0] += hv.x * wv.z; acc[3][0] += hv.x * wv.w;
                acc[0][1] += hv.y * wv.x; acc[1][1] += hv.y * wv.y; acc[2][1] += hv.y * wv.z; acc[3][1] += hv.y * wv.w;
                acc[0][2] += hv.z * wv.x; acc[1][2] += hv.z * wv.y; acc[2][2] += hv.z * wv.z; acc[3][2] += hv.z * wv.w;
                acc[0][3] += hv.w * wv.x; acc[1][3] += hv.w * wv.y; acc[2][3] += hv.w * wv.z; acc[3][3] += hv.w * wv.w;
            }
        }
    }
    const float a_out = 0.990049834f;
    #pragma unroll
    for (int j = 0; j < 4; j++) {
        int b = bg * 4 + j;
        size_t sidx = ((size_t)b * IC + i) * NDIM + kg;
        float jg = tanhf(acc[0][j]), ig = sigf(acc[1][j]), fg = sigf(acc[2][j]), og = sigf(acc[3][j]);
        float alpha_m = expf(-7.8125e-5f * jg);
        float ro = expf(-1.5625e-4f * ig);
        float b_ad = ro * 0.1f + (1.0f - ro) * ig;
        float Bth = 0.04f + 1.8f * b_ad;
        float hprev = 0.0f, cprev = 0.0f;
        if (t > 0) { hprev = out[((size_t)(b * TT + (t - 1)) * IC + i) * NDIM + kg]; cprev = cfin[sidx]; }
        float mem = jg * alpha_m + (1.0f - alpha_m) * hprev - Bth * ig * 0.01f;
        float spike = (mem - Bth) > 0.0f ? 1.0f : 0.0f;
        float mem_o = mem * a_out + (1.0f - a_out) * spike + 0.08f;
        float cn = cprev * fg + ig * spike * mem_o;
        float hn = og * tanhf(cn);
        cfin[sidx] = cn;
        out[((size_t)(b * TT + t) * IC + i) * NDIM + kg] = hn;
        if (t == TT - 1) hfin[sidx] = hn;
    }
}

extern "C" void kernel_launch(void* const* d_in, const int* in_sizes, int n_in,
                              void* d_out, int out_size, void* d_ws, size_t ws_size,
                              hipStream_t stream) {
    const float* x   = (const float*)d_in[0];
    const float* Uj  = (const float*)d_in[1];
    const float* Ui_ = (const float*)d_in[2];
    const float* Uf  = (const float*)d_in[3];
    const float* Uo  = (const float*)d_in[4];
    const float* Wj  = (const float*)d_in[5];
    const float* Wi  = (const float*)d_in[6];
    const float* Wf  = (const float*)d_in[7];
    const float* Wo  = (const float*)d_in[8];
    const float* bj  = (const float*)d_in[9];
    const float* bi_ = (const float*)d_in[10];
    const float* bf_ = (const float*)d_in[11];
    const float* bo  = (const float*)d_in[12];
    float* out = (float*)d_out;

    if (ws_size >= WS_NEED) {
        static bool attr_set = false;
        if (!attr_set) {   // opt-in to 160 KiB dynamic LDS (host-side, not captured)
            (void)hipFuncSetAttribute((const void*)es_persist,
                                      hipFuncAttributeMaxDynamicSharedMemorySize, SMEM_BYTES);
            attr_set = true;
        }
        pack_w<<<dim3(2048), dim3(256), 0, stream>>>(Wj, Wi, Wf, Wo, (uint4*)d_ws);
        es_persist<<<dim3(IC, 16), dim3(256), SMEM_BYTES, stream>>>(
            x, Uj, Ui_, Uf, Uo, (const uint4*)d_ws, bj, bi_, bf_, bo, out);
    } else {
        for (int t = 0; t < TT; t++) {
            step_kernel_valu<<<dim3(IC, NDIM / KT), dim3(256), 0, stream>>>(
                t, x, Uj, Ui_, Uf, Uo, Wj, Wi, Wf, Wo, bj, bi_, bf_, bo, out);
        }
    }
}

// Round 5
// 1533.447 us; speedup vs baseline: 2.5385x; 2.5385x over previous
//
#include <hip/hip_runtime.h>
#include <hip/hip_bf16.h>

typedef __hip_bfloat16 bf16;
typedef __attribute__((ext_vector_type(8))) short short8;
typedef __attribute__((ext_vector_type(4))) float float4v;

#define BSZ 32
#define TT  128
#define IC  16
#define NDIM 512
#define WS_NEED ((size_t)4 * IC * NDIM * NDIM * 2)   // 33.55 MB bf16 packed weights

__device__ __forceinline__ float sigf(float v) { return 1.0f / (1.0f + expf(-v)); }
__device__ __forceinline__ unsigned f2bfb(float f) {
    bf16 h = __float2bfloat16(f);
    return (unsigned)*reinterpret_cast<unsigned short*>(&h);
}

// ---------------- one-time weight pack: fp32 W -> bf16 MFMA B-fragments ----
// uint4 index = ((blk*16 + kstep)*64 + lane), blk = (g*IC + i)*32 + nt16
// lane frag elems j=0..7:  W_g[i][ kstep*32 + (lane>>4)*8 + j ][ nt16*16 + (lane&15) ]
__global__ void pack_w(const float* __restrict__ Wj, const float* __restrict__ Wi,
                       const float* __restrict__ Wf, const float* __restrict__ Wo,
                       uint4* __restrict__ wpk)
{
    __shared__ float tile[NDIM][17];
    const int blk  = blockIdx.x;
    const int nt16 = blk & 31;
    const int i    = (blk >> 5) & 15;
    const int g    = blk >> 9;
    const float* W = (g == 0) ? Wj : (g == 1) ? Wi : (g == 2) ? Wf : Wo;
    const float* base = W + (size_t)i * NDIM * NDIM + nt16 * 16;
    const int tid = threadIdx.x;

    #pragma unroll
    for (int r = 0; r < 2; r++) {
        int n = tid + r * 256;
        const float4* p = (const float4*)(base + (size_t)n * NDIM);
        float4 v0 = p[0], v1 = p[1], v2 = p[2], v3 = p[3];
        float* d = &tile[n][0];
        d[0]=v0.x; d[1]=v0.y; d[2]=v0.z; d[3]=v0.w;
        d[4]=v1.x; d[5]=v1.y; d[6]=v1.z; d[7]=v1.w;
        d[8]=v2.x; d[9]=v2.y; d[10]=v2.z; d[11]=v2.w;
        d[12]=v3.x; d[13]=v3.y; d[14]=v3.z; d[15]=v3.w;
    }
    __syncthreads();
    #pragma unroll
    for (int p = 0; p < 4; p++) {
        int f = p * 256 + tid;
        int kstep = f >> 6, L = f & 63;
        int quad = L >> 4, col = L & 15;
        int nr = kstep * 32 + quad * 8;
        unsigned u[4];
        #pragma unroll
        for (int w = 0; w < 4; w++) {
            unsigned lo = f2bfb(tile[nr + 2 * w][col]);
            unsigned hi = f2bfb(tile[nr + 2 * w + 1][col]);
            u[w] = lo | (hi << 16);
        }
        wpk[(size_t)blk * 1024 + (size_t)kstep * 64 + L] = make_uint4(u[0], u[1], u[2], u[3]);
    }
}

// ---------------- per-step MFMA kernel (deep register prefetch) ----------------
// 1 block/CU, 1 wave/SIMD -> the whole VGPR file is ours. Issue ALL loads for the
// step up front (16 h-float4 + 64 B-fragments + c/x/bias scalars ~ 80 VMEM ops in
// flight per lane) so the single wave exposes load latency once instead of 16 times.
__launch_bounds__(256, 1)
__global__ void step_mfma(int t,
    const float* __restrict__ x,
    const float* __restrict__ Uj, const float* __restrict__ Ui, const float* __restrict__ Uf, const float* __restrict__ Uo,
    const uint4* __restrict__ wpk,
    const float* __restrict__ bj, const float* __restrict__ bi, const float* __restrict__ bfp, const float* __restrict__ bo,
    float* __restrict__ out)
{
    __shared__ bf16 h_lds[BSZ][NDIM + 8];   // row stride 520 bf16 = 1040 B (proven layout)

    const int i   = blockIdx.x;        // channel
    const int kt  = blockIdx.y;        // 32-col tile
    const int tid = threadIdx.x;
    const int wid = tid >> 6, L = tid & 63;
    const int quad = L >> 4, c15 = L & 15;
    const int nt16 = kt * 2 + (wid & 1);   // 16-col tile owned by this wave
    const int Mh   = (wid >> 1) * 16;      // batch half

    float* hfin = out + (size_t)BSZ * TT * IC * NDIM;
    float* cfin = hfin + (size_t)BSZ * IC * NDIM;

    const int n = nt16 * 16 + c15;
    const size_t un = (size_t)i * NDIM + n;

    // ---- early scalar loads: biases/U, x, and the c-state (hoists the dependent
    //      cfin read that used to stall inside the epilogue)
    const float u0 = Uj[un], u1 = Ui[un], u2 = Uf[un], u3 = Uo[un];
    const float c0 = bj[un], c1 = bi[un], c2 = bfp[un], c3 = bo[un];
    float xv[4], cpv[4];
    size_t sidx[4];
    #pragma unroll
    for (int r = 0; r < 4; r++) {
        int b = Mh + quad * 4 + r;
        sidx[r] = ((size_t)b * IC + i) * NDIM + n;
        xv[r]  = x[(size_t)(b * TT + t) * IC + i];
        cpv[r] = (t > 0) ? cfin[sidx[r]] : 0.0f;
    }

    float4v acc0 = {0,0,0,0}, acc1 = {0,0,0,0}, acc2 = {0,0,0,0}, acc3 = {0,0,0,0};

    if (t > 0) {
        // ---- issue h[:, t-1] loads (16 x dwordx4 per lane, coalesced)
        const int sb = tid >> 3, sn0 = (tid & 7) * 64;
        const float4* src = (const float4*)(out + ((size_t)(sb * TT + (t - 1)) * IC + i) * NDIM + sn0);
        float4 hv[16];
        #pragma unroll
        for (int q = 0; q < 16; q++) hv[q] = src[q];

        // ---- issue ALL B-fragment loads (4 gates x 16 ks = 64 x dwordx4 per lane)
        const size_t gstride = (size_t)IC * 32 * 1024;                    // uint4s per gate
        const uint4* bbase = wpk + ((size_t)i * 32 + nt16) * 1024 + L;    // gate 0 base
        short8 bf0[16], bf1[16], bf2[16], bf3[16];
        #pragma unroll
        for (int ks = 0; ks < 16; ks++) bf0[ks] = *(const short8*)(bbase + (size_t)ks * 64);
        #pragma unroll
        for (int ks = 0; ks < 16; ks++) bf1[ks] = *(const short8*)(bbase + gstride + (size_t)ks * 64);
        #pragma unroll
        for (int ks = 0; ks < 16; ks++) bf2[ks] = *(const short8*)(bbase + 2 * gstride + (size_t)ks * 64);
        #pragma unroll
        for (int ks = 0; ks < 16; ks++) bf3[ks] = *(const short8*)(bbase + 3 * gstride + (size_t)ks * 64);

        // ---- pack h -> bf16 LDS (consumes only the h loads; B loads stay in flight)
        #pragma unroll
        for (int q = 0; q < 8; q++) {
            float4 a = hv[2 * q], bb = hv[2 * q + 1];
            unsigned v0 = f2bfb(a.x)  | (f2bfb(a.y)  << 16);
            unsigned v1 = f2bfb(a.z)  | (f2bfb(a.w)  << 16);
            unsigned v2 = f2bfb(bb.x) | (f2bfb(bb.y) << 16);
            unsigned v3 = f2bfb(bb.z) | (f2bfb(bb.w) << 16);
            *(uint4*)&h_lds[sb][sn0 + q * 8] = make_uint4(v0, v1, v2, v3);
        }
        __syncthreads();

        // ---- MFMA: A from LDS, B already (or soon) in registers
        const bf16* arow = &h_lds[Mh + c15][0];
        #pragma unroll
        for (int ks = 0; ks < 16; ks++) {
            short8 a = *(const short8*)(arow + ks * 32 + quad * 8);
            acc0 = __builtin_amdgcn_mfma_f32_16x16x32_bf16(a, bf0[ks], acc0, 0, 0, 0);
            acc1 = __builtin_amdgcn_mfma_f32_16x16x32_bf16(a, bf1[ks], acc1, 0, 0, 0);
            acc2 = __builtin_amdgcn_mfma_f32_16x16x32_bf16(a, bf2[ks], acc2, 0, 0, 0);
            acc3 = __builtin_amdgcn_mfma_f32_16x16x32_bf16(a, bf3[ks], acc3, 0, 0, 0);
        }
    }

    // ---- epilogue (all 4 gates resident in this wave's acc regs)
    const float a_out = 0.990049834f;     // exp(-0.01)
    #pragma unroll
    for (int r = 0; r < 4; r++) {
        const int b = Mh + quad * 4 + r;  // C-layout row

        float jg = tanhf(acc0[r] + c0 + xv[r] * u0);
        float ig = sigf (acc1[r] + c1 + xv[r] * u1);
        float fg = sigf (acc2[r] + c2 + xv[r] * u2);
        float og = sigf (acc3[r] + c3 + xv[r] * u3);

        float alpha_m = expf(-7.8125e-5f * jg);
        float ro      = expf(-1.5625e-4f * ig);
        float b_ad    = ro * 0.1f + (1.0f - ro) * ig;
        float Bth     = 0.04f + 1.8f * b_ad;

        float hprev = 0.0f;
        if (t > 0)   // coeff (1-alpha)~7.8e-5: bf16 is free (same as verified path)
            hprev = __bfloat162float(h_lds[b][n]);

        float mem   = jg * alpha_m + (1.0f - alpha_m) * hprev - Bth * ig * 0.01f;
        float spike = (mem - Bth) > 0.0f ? 1.0f : 0.0f;
        float mem_o = mem * a_out + (1.0f - a_out) * spike + 0.08f;

        float cn = cpv[r] * fg + ig * spike * mem_o;
        float hn = og * tanhf(cn);

        cfin[sidx[r]] = cn;
        out[((size_t)(b * TT + t) * IC + i) * NDIM + n] = hn;
        if (t == TT - 1) hfin[sidx[r]] = hn;
    }
}

// ---------------- fallback (proven R5 path, used only if ws too small) ----
#define KT 32
#define NC 64
__launch_bounds__(256)
__global__ void step_kernel_valu(int t,
    const float* __restrict__ x,
    const float* __restrict__ Uj, const float* __restrict__ Ui, const float* __restrict__ Uf, const float* __restrict__ Uo,
    const float* __restrict__ Wj, const float* __restrict__ Wi, const float* __restrict__ Wf, const float* __restrict__ Wo,
    const float* __restrict__ bj, const float* __restrict__ bi, const float* __restrict__ bfp, const float* __restrict__ bo,
    float* __restrict__ out)
{
    __shared__ float w_lds[NC][KT * 4 + 4];
    __shared__ float h_lds[NC][BSZ + 4];
    const int i = blockIdx.x, k0 = blockIdx.y * KT, tid = threadIdx.x;
    const int kl = tid & 31, bg = tid >> 5, kg = k0 + kl;
    float* hfin = out + (size_t)BSZ * TT * IC * NDIM;
    float* cfin = hfin + (size_t)BSZ * IC * NDIM;
    float acc[4][4];
    {
        size_t uidx = (size_t)i * NDIM + kg;
        float u0 = Uj[uidx], u1 = Ui[uidx], u2 = Uf[uidx], u3 = Uo[uidx];
        float c0 = bj[uidx], c1 = bi[uidx], c2 = bfp[uidx], c3 = bo[uidx];
        #pragma unroll
        for (int j = 0; j < 4; j++) {
            int b = bg * 4 + j;
            float xv = x[(size_t)(b * TT + t) * IC + i];
            acc[0][j] = c0 + xv * u0; acc[1][j] = c1 + xv * u1;
            acc[2][j] = c2 + xv * u2; acc[3][j] = c3 + xv * u3;
        }
    }
    if (t > 0) {
        for (int n0 = 0; n0 < NDIM; n0 += NC) {
            __syncthreads();
            {
                int g = tid >> 6, nn = tid & 63;
                const float* Wp = (g == 0) ? Wj : (g == 1) ? Wi : (g == 2) ? Wf : Wo;
                const float4* p = (const float4*)(Wp + ((size_t)i * NDIM + (size_t)(n0 + nn)) * NDIM + k0);
                #pragma unroll
                for (int q = 0; q < 8; q++) {
                    float4 v = p[q];
                    w_lds[nn][(q * 4 + 0) * 4 + g] = v.x; w_lds[nn][(q * 4 + 1) * 4 + g] = v.y;
                    w_lds[nn][(q * 4 + 2) * 4 + g] = v.z; w_lds[nn][(q * 4 + 3) * 4 + g] = v.w;
                }
            }
            {
                int b = tid >> 3, nb = (tid & 7) * 8;
                const float4* ph = (const float4*)(out + ((size_t)(b * TT + (t - 1)) * IC + i) * NDIM + n0 + nb);
                float4 h0 = ph[0], h1 = ph[1];
                h_lds[nb + 0][b] = h0.x; h_lds[nb + 1][b] = h0.y; h_lds[nb + 2][b] = h0.z; h_lds[nb + 3][b] = h0.w;
                h_lds[nb + 4][b] = h1.x; h_lds[nb + 5][b] = h1.y; h_lds[nb + 6][b] = h1.z; h_lds[nb + 7][b] = h1.w;
            }
            __syncthreads();
            #pragma unroll 8
            for (int nn = 0; nn < NC; nn++) {
                float4 wv = *(const float4*)&w_lds[nn][kl * 4];
                float4 hv = *(const float4*)&h_lds[nn][bg * 4];
                acc[0][0] += hv.x * wv.x; acc[1][0] += hv.x * wv.y; acc[2][0] += hv.x * wv.z; acc[3][0] += hv.x * wv.w;
                acc[0][1] += hv.y * wv.x; acc[1][1] += hv.y * wv.y; acc[2][1] += hv.y * wv.z; acc[3][1] += hv.y * wv.w;
                acc[0][2] += hv.z * wv.x; acc[1][2] += hv.z * wv.y; acc[2][2] += hv.z * wv.z; acc[3][2] += hv.z * wv.w;
                acc[0][3] += hv.w * wv.x; acc[1][3] += hv.w * wv.y; acc[2][3] += hv.w * wv.z; acc[3][3] += hv.w * wv.w;
            }
        }
    }
    const float a_out = 0.990049834f;
    #pragma unroll
    for (int j = 0; j < 4; j++) {
        int b = bg * 4 + j;
        size_t sidx = ((size_t)b * IC + i) * NDIM + kg;
        float jg = tanhf(acc[0][j]), ig = sigf(acc[1][j]), fg = sigf(acc[2][j]), og = sigf(acc[3][j]);
        float alpha_m = expf(-7.8125e-5f * jg);
        float ro = expf(-1.5625e-4f * ig);
        float b_ad = ro * 0.1f + (1.0f - ro) * ig;
        float Bth = 0.04f + 1.8f * b_ad;
        float hprev = 0.0f, cprev = 0.0f;
        if (t > 0) { hprev = out[((size_t)(b * TT + (t - 1)) * IC + i) * NDIM + kg]; cprev = cfin[sidx]; }
        float mem = jg * alpha_m + (1.0f - alpha_m) * hprev - Bth * ig * 0.01f;
        float spike = (mem - Bth) > 0.0f ? 1.0f : 0.0f;
        float mem_o = mem * a_out + (1.0f - a_out) * spike + 0.08f;
        float cn = cprev * fg + ig * spike * mem_o;
        float hn = og * tanhf(cn);
        cfin[sidx] = cn;
        out[((size_t)(b * TT + t) * IC + i) * NDIM + kg] = hn;
        if (t == TT - 1) hfin[sidx] = hn;
    }
}

extern "C" void kernel_launch(void* const* d_in, const int* in_sizes, int n_in,
                              void* d_out, int out_size, void* d_ws, size_t ws_size,
                              hipStream_t stream) {
    const float* x   = (const float*)d_in[0];
    const float* Uj  = (const float*)d_in[1];
    const float* Ui_ = (const float*)d_in[2];
    const float* Uf  = (const float*)d_in[3];
    const float* Uo  = (const float*)d_in[4];
    const float* Wj  = (const float*)d_in[5];
    const float* Wi  = (const float*)d_in[6];
    const float* Wf  = (const float*)d_in[7];
    const float* Wo  = (const float*)d_in[8];
    const float* bj  = (const float*)d_in[9];
    const float* bi_ = (const float*)d_in[10];
    const float* bf_ = (const float*)d_in[11];
    const float* bo  = (const float*)d_in[12];
    float* out = (float*)d_out;

    if (ws_size >= WS_NEED) {
        pack_w<<<dim3(2048), dim3(256), 0, stream>>>(Wj, Wi, Wf, Wo, (uint4*)d_ws);
        for (int t = 0; t < TT; t++) {
            step_mfma<<<dim3(IC, 16), dim3(256), 0, stream>>>(
                t, x, Uj, Ui_, Uf, Uo, (const uint4*)d_ws, bj, bi_, bf_, bo, out);
        }
    } else {
        for (int t = 0; t < TT; t++) {
            step_kernel_valu<<<dim3(IC, NDIM / KT), dim3(256), 0, stream>>>(
                t, x, Uj, Ui_, Uf, Uo, Wj, Wi, Wf, Wo, bj, bi_, bf_, bo, out);
        }
    }
}

// Round 6
// 924.354 us; speedup vs baseline: 4.2113x; 1.6589x over previous
//
#include <hip/hip_runtime.h>
#include <hip/hip_bf16.h>

typedef __hip_bfloat16 bf16;
typedef __attribute__((ext_vector_type(8))) short short8;
typedef __attribute__((ext_vector_type(4))) float float4v;

#define BSZ 32
#define TT  128
#define IC  16
#define NDIM 512
#define WS_NEED ((size_t)4 * IC * NDIM * NDIM * 2)   // 33.55 MB bf16 packed weights
#define SMEM_BYTES 131072                            // 32 KiB h + slack to force 1 block/CU

// Per-(channel,tile) flag words: g_flag[i*64+kt] = latest published step+1.
// SINGLE WRITER per word. All accesses via sc0 sc1 (MALL-coherent, bypass L1/L2)
// -> no cache-maintenance ops anywhere in the steady-state loop.
// Zeroed by pack_w (kernel-end writeback publishes zeros). Monotone within a run.
__device__ __attribute__((aligned(256))) unsigned g_flag[IC * 64];

__device__ __forceinline__ float sigf(float v) { return 1.0f / (1.0f + expf(-v)); }
__device__ __forceinline__ unsigned f2bfb(float f) {
    bf16 h = __float2bfloat16(f);
    return (unsigned)*reinterpret_cast<unsigned short*>(&h);
}

// ---------------- one-time weight pack: fp32 W -> bf16 MFMA B-fragments ----
// uint4 index = ((blk*16 + kstep)*64 + lane), blk = (g*IC + i)*32 + nt16
// lane frag elems j=0..7:  W_g[i][ kstep*32 + (lane>>4)*8 + j ][ nt16*16 + (lane&15) ]
__global__ void pack_w(const float* __restrict__ Wj, const float* __restrict__ Wi,
                       const float* __restrict__ Wf, const float* __restrict__ Wo,
                       uint4* __restrict__ wpk)
{
    __shared__ float tile[NDIM][17];
    const int blk  = blockIdx.x;
    if (blk == 0) {   // reset flags; visible via end-of-kernel writeback
        for (int k = threadIdx.x; k < IC * 64; k += 256) g_flag[k] = 0u;
    }
    const int nt16 = blk & 31;
    const int i    = (blk >> 5) & 15;
    const int g    = blk >> 9;
    const float* W = (g == 0) ? Wj : (g == 1) ? Wi : (g == 2) ? Wf : Wo;
    const float* base = W + (size_t)i * NDIM * NDIM + nt16 * 16;
    const int tid = threadIdx.x;

    #pragma unroll
    for (int r = 0; r < 2; r++) {
        int n = tid + r * 256;
        const float4* p = (const float4*)(base + (size_t)n * NDIM);
        float4 v0 = p[0], v1 = p[1], v2 = p[2], v3 = p[3];
        float* d = &tile[n][0];
        d[0]=v0.x; d[1]=v0.y; d[2]=v0.z; d[3]=v0.w;
        d[4]=v1.x; d[5]=v1.y; d[6]=v1.z; d[7]=v1.w;
        d[8]=v2.x; d[9]=v2.y; d[10]=v2.z; d[11]=v2.w;
        d[12]=v3.x; d[13]=v3.y; d[14]=v3.z; d[15]=v3.w;
    }
    __syncthreads();
    #pragma unroll
    for (int p = 0; p < 4; p++) {
        int f = p * 256 + tid;
        int kstep = f >> 6, L = f & 63;
        int quad = L >> 4, col = L & 15;
        int nr = kstep * 32 + quad * 8;
        unsigned u[4];
        #pragma unroll
        for (int w = 0; w < 4; w++) {
            unsigned lo = f2bfb(tile[nr + 2 * w][col]);
            unsigned hi = f2bfb(tile[nr + 2 * w + 1][col]);
            u[w] = lo | (hi << 16);
        }
        wpk[(size_t)blk * 1024 + (size_t)kstep * 64 + L] = make_uint4(u[0], u[1], u[2], u[3]);
    }
}

// ---------------- persistent all-timesteps kernel ----------------
// 256 blocks, 1 block/CU (forced by LDS request + ~380 VGPRs). Block = (channel
// i = bid&15, tile kt = bid>>4). Weights live in REGISTERS for all 128 steps
// (64 B-fragments = 256 VGPRs/lane). Cross-block h exchange is MALL-coherent:
// coalesced sc0 sc1 loads/stores only — no atomics, no wbl2/inv, no XCD
// assumptions. Single-writer flag words; spin caps -> fail loud, never hang.
__launch_bounds__(256, 1)
__global__ void es_persist(
    const float* __restrict__ x,
    const float* __restrict__ Uj, const float* __restrict__ Ui,
    const float* __restrict__ Uf, const float* __restrict__ Uo,
    const uint4* __restrict__ wpk,
    const float* __restrict__ bj, const float* __restrict__ bi,
    const float* __restrict__ bfp, const float* __restrict__ bo,
    float* __restrict__ out)
{
    extern __shared__ unsigned char smem[];
    unsigned char* h_base = smem;              // 32 KiB: row b at b*1024 B, chunk c at ((c^(b&7))<<4)

    const int bid = blockIdx.x;
    const int i   = bid & 15;                  // channel
    const int kt  = bid >> 4;                  // 32-col tile
    const int tid = threadIdx.x;
    const int wid = tid >> 6, L = tid & 63;
    const int quad = L >> 4, c15 = L & 15;
    const int ntl  = wid & 1;                  // local 16-col tile
    const int nt16 = kt * 2 + ntl;
    const int Mh   = (wid >> 1) * 16;          // batch half

    float* hfin = out + (size_t)BSZ * TT * IC * NDIM;
    float* cfin = hfin + (size_t)BSZ * IC * NDIM;

    // ---- prologue: this wave's B-fragments -> REGISTERS (once, stays all 128 steps)
    const size_t gstride = (size_t)IC * 32 * 1024;                    // uint4s per gate
    const uint4* bbase = wpk + ((size_t)i * 32 + nt16) * 1024 + L;
    short8 bfr0[16], bfr1[16], bfr2[16], bfr3[16];
    #pragma unroll
    for (int ks = 0; ks < 16; ks++) bfr0[ks] = *(const short8*)(bbase + (size_t)ks * 64);
    #pragma unroll
    for (int ks = 0; ks < 16; ks++) bfr1[ks] = *(const short8*)(bbase + gstride + (size_t)ks * 64);
    #pragma unroll
    for (int ks = 0; ks < 16; ks++) bfr2[ks] = *(const short8*)(bbase + 2 * gstride + (size_t)ks * 64);
    #pragma unroll
    for (int ks = 0; ks < 16; ks++) bfr3[ks] = *(const short8*)(bbase + 3 * gstride + (size_t)ks * 64);

    // ---- loop-invariant per-lane scalars
    const int n = nt16 * 16 + c15;
    const size_t un = (size_t)i * NDIM + n;
    const float u0 = Uj[un], u1 = Ui[un], u2 = Uf[un], u3 = Uo[un];
    const float c0 = bj[un], c1 = bi[un], c2 = bfp[un], c3 = bo[un];
    const float a_out = 0.990049834f;          // exp(-0.01)

    float cc[4] = {0.f, 0.f, 0.f, 0.f};        // c-state in registers across all steps

    // gather mapping: pair-index p = round*256 + tid -> batch row r = round*4 + wid,
    // chunk c6 = tid&63 (8 floats). Per wave instruction: 64 lanes x 16B contiguous.
    const int c6 = tid & 63;
    const int swo_w = c6 * 8;                  // float offset within row

    #pragma unroll 1
    for (int t = 0; t < TT; t++) {
        float4v acc0 = {0,0,0,0}, acc1 = {0,0,0,0}, acc2 = {0,0,0,0}, acc3 = {0,0,0,0};

        // x loads depend on no other block: issue before the wait
        float xv[4];
        #pragma unroll
        for (int r = 0; r < 4; r++)
            xv[r] = x[(size_t)((Mh + quad * 4 + r) * TT + t) * IC + i];

        if (t > 0) {
            // ---- wait: lanes 0-15 of wave 0 poll 16 single-writer flags (MALL)
            if (wid == 0) {
                const unsigned* fp = &g_flag[(i << 6) + (L & 15)];
                bool need = (L < 16);
                unsigned v = 0;
                int spins = 0;
                while (__ballot((int)need) != 0ull) {
                    if (need) {
                        asm volatile("global_load_dword %0, %1, off sc0 sc1\n\ts_waitcnt vmcnt(0)"
                                     : "=v"(v) : "v"(fp) : "memory");
                        if (v >= (unsigned)t) need = false;
                    }
                    if (need) __builtin_amdgcn_s_sleep(2);
                    if (++spins > 20000) break;   // fail loud (bad data), never hang
                }
            }
            __syncthreads();

            // ---- gather h[:, t-1, i, :]: 16 coalesced sc0sc1 dwordx4, all in flight
            float4v hva[8], hvb[8];
            #pragma unroll
            for (int rr = 0; rr < 8; rr++) {
                const int row = rr * 4 + wid;
                const float* s = out + ((size_t)(row * TT + (t - 1)) * IC + i) * NDIM + swo_w;
                asm volatile("global_load_dwordx4 %0, %1, off sc0 sc1" : "=v"(hva[rr]) : "v"(s));
                asm volatile("global_load_dwordx4 %0, %1, off sc0 sc1" : "=v"(hvb[rr]) : "v"(s + 4));
            }
            asm volatile("s_waitcnt vmcnt(0)" ::: "memory");
            __builtin_amdgcn_sched_barrier(0);

            // ---- bf16-pack + swizzled LDS write (per wave: one full row sweep)
            #pragma unroll
            for (int rr = 0; rr < 8; rr++) {
                const int row = rr * 4 + wid;
                unsigned v0 = f2bfb(hva[rr][0]) | (f2bfb(hva[rr][1]) << 16);
                unsigned v1 = f2bfb(hva[rr][2]) | (f2bfb(hva[rr][3]) << 16);
                unsigned v2 = f2bfb(hvb[rr][0]) | (f2bfb(hvb[rr][1]) << 16);
                unsigned v3 = f2bfb(hvb[rr][2]) | (f2bfb(hvb[rr][3]) << 16);
                *(uint4*)(h_base + row * 1024 + ((c6 ^ (row & 7)) << 4)) = make_uint4(v0, v1, v2, v3);
            }
            __syncthreads();

            // ---- MFMA: A from swizzled h LDS, B resident in registers
            const int arow = Mh + c15;
            const unsigned char* aptr = h_base + arow * 1024;
            const int ax = arow & 7;
            #pragma unroll
            for (int ks = 0; ks < 16; ks++) {
                short8 a = *(const short8*)(aptr + (((ks * 4 + quad) ^ ax) << 4));
                acc0 = __builtin_amdgcn_mfma_f32_16x16x32_bf16(a, bfr0[ks], acc0, 0, 0, 0);
                acc1 = __builtin_amdgcn_mfma_f32_16x16x32_bf16(a, bfr1[ks], acc1, 0, 0, 0);
                acc2 = __builtin_amdgcn_mfma_f32_16x16x32_bf16(a, bfr2[ks], acc2, 0, 0, 0);
                acc3 = __builtin_amdgcn_mfma_f32_16x16x32_bf16(a, bfr3[ks], acc3, 0, 0, 0);
            }
        }

        // ---- epilogue (all 4 gates resident in this wave's acc regs)
        #pragma unroll
        for (int r = 0; r < 4; r++) {
            const int b = Mh + quad * 4 + r;    // C-layout row

            float jg = tanhf(acc0[r] + c0 + xv[r] * u0);
            float ig = sigf (acc1[r] + c1 + xv[r] * u1);
            float fg = sigf (acc2[r] + c2 + xv[r] * u2);
            float og = sigf (acc3[r] + c3 + xv[r] * u3);

            float alpha_m = expf(-7.8125e-5f * jg);
            float ro      = expf(-1.5625e-4f * ig);
            float b_ad    = ro * 0.1f + (1.0f - ro) * ig;
            float Bth     = 0.04f + 1.8f * b_ad;

            float hprev = 0.0f;
            if (t > 0)   // coeff (1-alpha)~7.8e-5: bf16 is free (same as verified path)
                hprev = __bfloat162float(*(const bf16*)(h_base + b * 1024
                            + (((n >> 3) ^ (b & 7)) << 4) + (n & 7) * 2));

            float mem   = jg * alpha_m + (1.0f - alpha_m) * hprev - Bth * ig * 0.01f;
            float spike = (mem - Bth) > 0.0f ? 1.0f : 0.0f;
            float mem_o = mem * a_out + (1.0f - a_out) * spike + 0.08f;

            float cn = cc[r] * fg + ig * spike * mem_o;
            float hn = og * tanhf(cn);
            cc[r] = cn;

            // MALL-coherent (write-through) h store; coalesced 64B per quad
            float* hp = out + ((size_t)(b * TT + t) * IC + i) * NDIM + n;
            asm volatile("global_store_dword %0, %1, off sc0 sc1" :: "v"(hp), "v"(hn) : "memory");
            if (t == TT - 1) {
                size_t sidx = ((size_t)b * IC + i) * NDIM + n;
                cfin[sidx] = cn;
                hfin[sidx] = hn;
            }
        }

        // ---- publish h(t): drain sc0sc1 stores (ACK at MALL), join, set flag word
        if (t < TT - 1) {
            asm volatile("s_waitcnt vmcnt(0)" ::: "memory");
            __syncthreads();
            if (tid == 0) {
                unsigned tv = (unsigned)(t + 1);
                const unsigned* fp = &g_flag[(i << 6) + kt];
                asm volatile("global_store_dword %0, %1, off sc0 sc1" :: "v"(fp), "v"(tv) : "memory");
            }
        }
    }
}

// ---------------- fallback (proven R5 path, used only if ws too small) ----
#define KT 32
#define NC 64
__launch_bounds__(256)
__global__ void step_kernel_valu(int t,
    const float* __restrict__ x,
    const float* __restrict__ Uj, const float* __restrict__ Ui, const float* __restrict__ Uf, const float* __restrict__ Uo,
    const float* __restrict__ Wj, const float* __restrict__ Wi, const float* __restrict__ Wf, const float* __restrict__ Wo,
    const float* __restrict__ bj, const float* __restrict__ bi, const float* __restrict__ bfp, const float* __restrict__ bo,
    float* __restrict__ out)
{
    __shared__ float w_lds[NC][KT * 4 + 4];
    __shared__ float h_lds[NC][BSZ + 4];
    const int i = blockIdx.x, k0 = blockIdx.y * KT, tid = threadIdx.x;
    const int kl = tid & 31, bg = tid >> 5, kg = k0 + kl;
    float* hfin = out + (size_t)BSZ * TT * IC * NDIM;
    float* cfin = hfin + (size_t)BSZ * IC * NDIM;
    float acc[4][4];
    {
        size_t uidx = (size_t)i * NDIM + kg;
        float u0 = Uj[uidx], u1 = Ui[uidx], u2 = Uf[uidx], u3 = Uo[uidx];
        float c0 = bj[uidx], c1 = bi[uidx], c2 = bfp[uidx], c3 = bo[uidx];
        #pragma unroll
        for (int j = 0; j < 4; j++) {
            int b = bg * 4 + j;
            float xv = x[(size_t)(b * TT + t) * IC + i];
            acc[0][j] = c0 + xv * u0; acc[1][j] = c1 + xv * u1;
            acc[2][j] = c2 + xv * u2; acc[3][j] = c3 + xv * u3;
        }
    }
    if (t > 0) {
        for (int n0 = 0; n0 < NDIM; n0 += NC) {
            __syncthreads();
            {
                int g = tid >> 6, nn = tid & 63;
                const float* Wp = (g == 0) ? Wj : (g == 1) ? Wi : (g == 2) ? Wf : Wo;
                const float4* p = (const float4*)(Wp + ((size_t)i * NDIM + (size_t)(n0 + nn)) * NDIM + k0);
                #pragma unroll
                for (int q = 0; q < 8; q++) {
                    float4 v = p[q];
                    w_lds[nn][(q * 4 + 0) * 4 + g] = v.x; w_lds[nn][(q * 4 + 1) * 4 + g] = v.y;
                    w_lds[nn][(q * 4 + 2) * 4 + g] = v.z; w_lds[nn][(q * 4 + 3) * 4 + g] = v.w;
                }
            }
            {
                int b = tid >> 3, nb = (tid & 7) * 8;
                const float4* ph = (const float4*)(out + ((size_t)(b * TT + (t - 1)) * IC + i) * NDIM + n0 + nb);
                float4 h0 = ph[0], h1 = ph[1];
                h_lds[nb + 0][b] = h0.x; h_lds[nb + 1][b] = h0.y; h_lds[nb + 2][b] = h0.z; h_lds[nb + 3][b] = h0.w;
                h_lds[nb + 4][b] = h1.x; h_lds[nb + 5][b] = h1.y; h_lds[nb + 6][b] = h1.z; h_lds[nb + 7][b] = h1.w;
            }
            __syncthreads();
            #pragma unroll 8
            for (int nn = 0; nn < NC; nn++) {
                float4 wv = *(const float4*)&w_lds[nn][kl * 4];
                float4 hv = *(const float4*)&h_lds[nn][bg * 4];
                acc[0][0] += hv.x * wv.x; acc[1][0] += hv.x * wv.y; acc[2][0] += hv.x * wv.z; acc[3][0] += hv.x * wv.w;
                acc[0][1] += hv.y * wv.x; acc[1][1] += hv.y * wv.y; acc[2][1] += hv.y * wv.z; acc[3][1] += hv.y * wv.w;
                acc[0][2] += hv.z * wv.x; acc[1][2] += hv.z * wv.y; acc[2][2] += hv.z * wv.z; acc[3][2] += hv.z * wv.w;
                acc[0][3] += hv.w * wv.x; acc[1][3] += hv.w * wv.y; acc[2][3] += hv.w * wv.z; acc[3][3] += hv.w * wv.w;
            }
        }
    }
    const float a_out = 0.990049834f;
    #pragma unroll
    for (int j = 0; j < 4; j++) {
        int b = bg * 4 + j;
        size_t sidx = ((size_t)b * IC + i) * NDIM + kg;
        float jg = tanhf(acc[0][j]), ig = sigf(acc[1][j]), fg = sigf(acc[2][j]), og = sigf(acc[3][j]);
        float alpha_m = expf(-7.8125e-5f * jg);
        float ro = expf(-1.5625e-4f * ig);
        float b_ad = ro * 0.1f + (1.0f - ro) * ig;
        float Bth = 0.04f + 1.8f * b_ad;
        float hprev = 0.0f, cprev = 0.0f;
        if (t > 0) { hprev = out[((size_t)(b * TT + (t - 1)) * IC + i) * NDIM + kg]; cprev = cfin[sidx]; }
        float mem = jg * alpha_m + (1.0f - alpha_m) * hprev - Bth * ig * 0.01f;
        float spike = (mem - Bth) > 0.0f ? 1.0f : 0.0f;
        float mem_o = mem * a_out + (1.0f - a_out) * spike + 0.08f;
        float cn = cprev * fg + ig * spike * mem_o;
        float hn = og * tanhf(cn);
        cfin[sidx] = cn;
        out[((size_t)(b * TT + t) * IC + i) * NDIM + kg] = hn;
        if (t == TT - 1) hfin[sidx] = hn;
    }
}

extern "C" void kernel_launch(void* const* d_in, const int* in_sizes, int n_in,
                              void* d_out, int out_size, void* d_ws, size_t ws_size,
                              hipStream_t stream) {
    const float* x   = (const float*)d_in[0];
    const float* Uj  = (const float*)d_in[1];
    const float* Ui_ = (const float*)d_in[2];
    const float* Uf  = (const float*)d_in[3];
    const float* Uo  = (const float*)d_in[4];
    const float* Wj  = (const float*)d_in[5];
    const float* Wi  = (const float*)d_in[6];
    const float* Wf  = (const float*)d_in[7];
    const float* Wo  = (const float*)d_in[8];
    const float* bj  = (const float*)d_in[9];
    const float* bi_ = (const float*)d_in[10];
    const float* bf_ = (const float*)d_in[11];
    const float* bo  = (const float*)d_in[12];
    float* out = (float*)d_out;

    if (ws_size >= WS_NEED) {
        static bool attr_set = false;
        if (!attr_set) {   // opt-in to 128 KiB dynamic LDS (host-side, not captured)
            (void)hipFuncSetAttribute((const void*)es_persist,
                                      hipFuncAttributeMaxDynamicSharedMemorySize, SMEM_BYTES);
            attr_set = true;
        }
        pack_w<<<dim3(2048), dim3(256), 0, stream>>>(Wj, Wi, Wf, Wo, (uint4*)d_ws);
        es_persist<<<dim3(256), dim3(256), SMEM_BYTES, stream>>>(
            x, Uj, Ui_, Uf, Uo, (const uint4*)d_ws, bj, bi_, bf_, bo, out);
    } else {
        for (int t = 0; t < TT; t++) {
            step_kernel_valu<<<dim3(IC, NDIM / KT), dim3(256), 0, stream>>>(
                t, x, Uj, Ui_, Uf, Uo, Wj, Wi, Wf, Wo, bj, bi_, bf_, bo, out);
        }
    }
}

// Round 7
// 879.443 us; speedup vs baseline: 4.4263x; 1.0511x over previous
//
#include <hip/hip_runtime.h>
#include <hip/hip_bf16.h>

typedef __hip_bfloat16 bf16;
typedef unsigned short ushort_t;
typedef __attribute__((ext_vector_type(8))) short short8;
typedef __attribute__((ext_vector_type(4))) float float4v;

#define BSZ 32
#define TT  128
#define IC  16
#define NDIM 512
#define WS_NEED ((size_t)4 * IC * NDIM * NDIM * 2)   // 33.55 MB bf16 packed weights
#define SMEM_BYTES 131072                            // 32 KiB h + slack to force 1 block/CU

// Per-(channel,tile) flag words: g_flag[i*64+kt] = latest published step+1.
// SINGLE WRITER per word; all accesses sc0 sc1 (MALL-coherent). Zeroed by pack_w.
__device__ __attribute__((aligned(256))) unsigned g_flag[IC * 64];
// bf16 h exchange buffer, double-buffered by step parity. Written/read ONLY with
// sc0 sc1 (never L2-cached -> no staleness possible). 1 MB static.
__device__ __attribute__((aligned(256))) ushort_t g_hx[2][IC][BSZ * NDIM];

__device__ __forceinline__ float sigf(float v) { return 1.0f / (1.0f + expf(-v)); }
__device__ __forceinline__ unsigned f2bfb(float f) {
    bf16 h = __float2bfloat16(f);
    return (unsigned)*reinterpret_cast<unsigned short*>(&h);
}

// ---------------- one-time weight pack: fp32 W -> bf16 MFMA B-fragments ----
// uint4 index = ((blk*16 + kstep)*64 + lane), blk = (g*IC + i)*32 + nt16
// lane frag elems j=0..7:  W_g[i][ kstep*32 + (lane>>4)*8 + j ][ nt16*16 + (lane&15) ]
__global__ void pack_w(const float* __restrict__ Wj, const float* __restrict__ Wi,
                       const float* __restrict__ Wf, const float* __restrict__ Wo,
                       uint4* __restrict__ wpk)
{
    __shared__ float tile[NDIM][17];
    const int blk  = blockIdx.x;
    if (blk == 0) {   // reset flags; visible via end-of-kernel writeback
        for (int k = threadIdx.x; k < IC * 64; k += 256) g_flag[k] = 0u;
    }
    const int nt16 = blk & 31;
    const int i    = (blk >> 5) & 15;
    const int g    = blk >> 9;
    const float* W = (g == 0) ? Wj : (g == 1) ? Wi : (g == 2) ? Wf : Wo;
    const float* base = W + (size_t)i * NDIM * NDIM + nt16 * 16;
    const int tid = threadIdx.x;

    #pragma unroll
    for (int r = 0; r < 2; r++) {
        int n = tid + r * 256;
        const float4* p = (const float4*)(base + (size_t)n * NDIM);
        float4 v0 = p[0], v1 = p[1], v2 = p[2], v3 = p[3];
        float* d = &tile[n][0];
        d[0]=v0.x; d[1]=v0.y; d[2]=v0.z; d[3]=v0.w;
        d[4]=v1.x; d[5]=v1.y; d[6]=v1.z; d[7]=v1.w;
        d[8]=v2.x; d[9]=v2.y; d[10]=v2.z; d[11]=v2.w;
        d[12]=v3.x; d[13]=v3.y; d[14]=v3.z; d[15]=v3.w;
    }
    __syncthreads();
    #pragma unroll
    for (int p = 0; p < 4; p++) {
        int f = p * 256 + tid;
        int kstep = f >> 6, L = f & 63;
        int quad = L >> 4, col = L & 15;
        int nr = kstep * 32 + quad * 8;
        unsigned u[4];
        #pragma unroll
        for (int w = 0; w < 4; w++) {
            unsigned lo = f2bfb(tile[nr + 2 * w][col]);
            unsigned hi = f2bfb(tile[nr + 2 * w + 1][col]);
            u[w] = lo | (hi << 16);
        }
        wpk[(size_t)blk * 1024 + (size_t)kstep * 64 + L] = make_uint4(u[0], u[1], u[2], u[3]);
    }
}

// ---------------- persistent all-timesteps kernel ----------------
// 256 blocks, 1 block/CU. Block = (channel i = bid&15, tile kt = bid>>4).
// Weights in REGISTERS all 128 steps. Cross-block h exchange: bf16 via g_hx
// (double-buffered), sc0 sc1 only. Single-writer flags; spin cap -> fail loud.
__launch_bounds__(256, 1)
__global__ void es_persist(
    const float* __restrict__ x,
    const float* __restrict__ Uj, const float* __restrict__ Ui,
    const float* __restrict__ Uf, const float* __restrict__ Uo,
    const uint4* __restrict__ wpk,
    const float* __restrict__ bj, const float* __restrict__ bi,
    const float* __restrict__ bfp, const float* __restrict__ bo,
    float* __restrict__ out)
{
    extern __shared__ unsigned char smem[];
    unsigned char* h_base = smem;              // 32 KiB: row b at b*1024 B, chunk c at ((c^(b&7))<<4)

    const int bid = blockIdx.x;
    const int i   = bid & 15;                  // channel
    const int kt  = bid >> 4;                  // 32-col tile
    const int tid = threadIdx.x;
    const int wid = tid >> 6, L = tid & 63;
    const int quad = L >> 4, c15 = L & 15;
    const int ntl  = wid & 1;                  // local 16-col tile
    const int nt16 = kt * 2 + ntl;
    const int Mh   = (wid >> 1) * 16;          // batch half

    float* hfin = out + (size_t)BSZ * TT * IC * NDIM;
    float* cfin = hfin + (size_t)BSZ * IC * NDIM;

    // ---- prologue: this wave's B-fragments -> REGISTERS (once, stays all 128 steps)
    const size_t gstride = (size_t)IC * 32 * 1024;                    // uint4s per gate
    const uint4* bbase = wpk + ((size_t)i * 32 + nt16) * 1024 + L;
    short8 bfr0[16], bfr1[16], bfr2[16], bfr3[16];
    #pragma unroll
    for (int ks = 0; ks < 16; ks++) bfr0[ks] = *(const short8*)(bbase + (size_t)ks * 64);
    #pragma unroll
    for (int ks = 0; ks < 16; ks++) bfr1[ks] = *(const short8*)(bbase + gstride + (size_t)ks * 64);
    #pragma unroll
    for (int ks = 0; ks < 16; ks++) bfr2[ks] = *(const short8*)(bbase + 2 * gstride + (size_t)ks * 64);
    #pragma unroll
    for (int ks = 0; ks < 16; ks++) bfr3[ks] = *(const short8*)(bbase + 3 * gstride + (size_t)ks * 64);

    // ---- loop-invariant per-lane scalars
    const int n = nt16 * 16 + c15;
    const size_t un = (size_t)i * NDIM + n;
    const float u0 = Uj[un], u1 = Ui[un], u2 = Uf[un], u3 = Uo[un];
    const float c0 = bj[un], c1 = bi[un], c2 = bfp[un], c3 = bo[un];
    const float a_out = 0.990049834f;          // exp(-0.01)

    float cc[4] = {0.f, 0.f, 0.f, 0.f};        // c-state in registers across all steps

    #pragma unroll 1
    for (int t = 0; t < TT; t++) {
        float4v acc0 = {0,0,0,0}, acc1 = {0,0,0,0}, acc2 = {0,0,0,0}, acc3 = {0,0,0,0};

        // x loads depend on no other block: issue before the wait
        float xv[4];
        #pragma unroll
        for (int r = 0; r < 4; r++)
            xv[r] = x[(size_t)((Mh + quad * 4 + r) * TT + t) * IC + i];

        if (t > 0) {
            // ---- per-wave detect: lanes 0-15 poll 16 single-writer flags (MALL).
            // No barrier needed after: pre-MFMA and pre-flag barriers order LDS reuse.
            {
                const unsigned* fp = &g_flag[(i << 6) + (L & 15)];
                bool need = (L < 16);
                unsigned v = 0;
                int spins = 0;
                while (__ballot((int)need) != 0ull) {
                    if (need) {
                        asm volatile("global_load_dword %0, %1, off sc0 sc1\n\ts_waitcnt vmcnt(0)"
                                     : "=v"(v) : "v"(fp) : "memory");
                        if (v >= (unsigned)t) need = false;
                    }
                    if (need) __builtin_amdgcn_s_sleep(1);
                    if (++spins > 40000) break;   // fail loud (bad data), never hang
                }
            }

            // ---- gather h(t-1) as bf16: 8 coalesced sc0sc1 dwordx4 per thread
            // (1 KB contiguous per wave instr), no conversion needed.
            const ushort_t* gsrc = &g_hx[(t - 1) & 1][i][0];
            float4v hg[8];
            #pragma unroll
            for (int q = 0; q < 8; q++) {
                const ushort_t* s = gsrc + (size_t)(q * 4 + wid) * NDIM + L * 8;
                asm volatile("global_load_dwordx4 %0, %1, off sc0 sc1" : "=v"(hg[q]) : "v"(s));
            }
            asm volatile("s_waitcnt vmcnt(0)" ::: "memory");
            __builtin_amdgcn_sched_barrier(0);

            // ---- swizzled LDS write (b128, conflict-free permutation per row)
            #pragma unroll
            for (int q = 0; q < 8; q++) {
                int b = q * 4 + wid;
                *(float4v*)(h_base + b * 1024 + ((L ^ (b & 7)) << 4)) = hg[q];
            }
            __syncthreads();

            // ---- MFMA: A from swizzled h LDS, B resident in registers
            const int arow = Mh + c15;
            const unsigned char* aptr = h_base + arow * 1024;
            const int ax = arow & 7;
            #pragma unroll
            for (int ks = 0; ks < 16; ks++) {
                short8 a = *(const short8*)(aptr + (((ks * 4 + quad) ^ ax) << 4));
                acc0 = __builtin_amdgcn_mfma_f32_16x16x32_bf16(a, bfr0[ks], acc0, 0, 0, 0);
                acc1 = __builtin_amdgcn_mfma_f32_16x16x32_bf16(a, bfr1[ks], acc1, 0, 0, 0);
                acc2 = __builtin_amdgcn_mfma_f32_16x16x32_bf16(a, bfr2[ks], acc2, 0, 0, 0);
                acc3 = __builtin_amdgcn_mfma_f32_16x16x32_bf16(a, bfr3[ks], acc3, 0, 0, 0);
            }
        }

        // ---- epilogue (all 4 gates resident in this wave's acc regs)
        ushort_t* gdst = &g_hx[t & 1][i][0];
        #pragma unroll
        for (int r = 0; r < 4; r++) {
            const int b = Mh + quad * 4 + r;    // C-layout row

            float jg = tanhf(acc0[r] + c0 + xv[r] * u0);
            float ig = sigf (acc1[r] + c1 + xv[r] * u1);
            float fg = sigf (acc2[r] + c2 + xv[r] * u2);
            float og = sigf (acc3[r] + c3 + xv[r] * u3);

            float alpha_m = expf(-7.8125e-5f * jg);
            float ro      = expf(-1.5625e-4f * ig);
            float b_ad    = ro * 0.1f + (1.0f - ro) * ig;
            float Bth     = 0.04f + 1.8f * b_ad;

            float hprev = 0.0f;
            if (t > 0)   // coeff (1-alpha)~7.8e-5: bf16 is free (same as verified path)
                hprev = __bfloat162float(*(const bf16*)(h_base + b * 1024
                            + (((n >> 3) ^ (b & 7)) << 4) + (n & 7) * 2));

            float mem   = jg * alpha_m + (1.0f - alpha_m) * hprev - Bth * ig * 0.01f;
            float spike = (mem - Bth) > 0.0f ? 1.0f : 0.0f;
            float mem_o = mem * a_out + (1.0f - a_out) * spike + 0.08f;

            float cn = cc[r] * fg + ig * spike * mem_o;
            float hn = og * tanhf(cn);
            cc[r] = cn;

            // bf16 h for the exchange (MALL, write-through) — same rounding as the
            // verified LDS path, so numerics are bit-identical.
            ushort_t* gp = gdst + (size_t)b * NDIM + n;
            unsigned hb = f2bfb(hn);
            asm volatile("global_store_short %0, %1, off sc0 sc1" :: "v"(gp), "v"(hb) : "memory");
            // fp32 h for the harness output: plain cached store (no in-kernel reader)
            out[((size_t)(b * TT + t) * IC + i) * NDIM + n] = hn;
            if (t == TT - 1) {
                size_t sidx = ((size_t)b * IC + i) * NDIM + n;
                cfin[sidx] = cn;
                hfin[sidx] = hn;
            }
        }

        // ---- publish h(t): drain stores (MALL ack), join, set flag word
        if (t < TT - 1) {
            asm volatile("s_waitcnt vmcnt(0)" ::: "memory");
            __syncthreads();
            if (tid == 0) {
                unsigned tv = (unsigned)(t + 1);
                const unsigned* fp = &g_flag[(i << 6) + kt];
                asm volatile("global_store_dword %0, %1, off sc0 sc1" :: "v"(fp), "v"(tv) : "memory");
            }
        }
    }
}

// ---------------- fallback (proven R5 path, used only if ws too small) ----
#define KT 32
#define NC 64
__launch_bounds__(256)
__global__ void step_kernel_valu(int t,
    const float* __restrict__ x,
    const float* __restrict__ Uj, const float* __restrict__ Ui, const float* __restrict__ Uf, const float* __restrict__ Uo,
    const float* __restrict__ Wj, const float* __restrict__ Wi, const float* __restrict__ Wf, const float* __restrict__ Wo,
    const float* __restrict__ bj, const float* __restrict__ bi, const float* __restrict__ bfp, const float* __restrict__ bo,
    float* __restrict__ out)
{
    __shared__ float w_lds[NC][KT * 4 + 4];
    __shared__ float h_lds[NC][BSZ + 4];
    const int i = blockIdx.x, k0 = blockIdx.y * KT, tid = threadIdx.x;
    const int kl = tid & 31, bg = tid >> 5, kg = k0 + kl;
    float* hfin = out + (size_t)BSZ * TT * IC * NDIM;
    float* cfin = hfin + (size_t)BSZ * IC * NDIM;
    float acc[4][4];
    {
        size_t uidx = (size_t)i * NDIM + kg;
        float u0 = Uj[uidx], u1 = Ui[uidx], u2 = Uf[uidx], u3 = Uo[uidx];
        float c0 = bj[uidx], c1 = bi[uidx], c2 = bfp[uidx], c3 = bo[uidx];
        #pragma unroll
        for (int j = 0; j < 4; j++) {
            int b = bg * 4 + j;
            float xv = x[(size_t)(b * TT + t) * IC + i];
            acc[0][j] = c0 + xv * u0; acc[1][j] = c1 + xv * u1;
            acc[2][j] = c2 + xv * u2; acc[3][j] = c3 + xv * u3;
        }
    }
    if (t > 0) {
        for (int n0 = 0; n0 < NDIM; n0 += NC) {
            __syncthreads();
            {
                int g = tid >> 6, nn = tid & 63;
                const float* Wp = (g == 0) ? Wj : (g == 1) ? Wi : (g == 2) ? Wf : Wo;
                const float4* p = (const float4*)(Wp + ((size_t)i * NDIM + (size_t)(n0 + nn)) * NDIM + k0);
                #pragma unroll
                for (int q = 0; q < 8; q++) {
                    float4 v = p[q];
                    w_lds[nn][(q * 4 + 0) * 4 + g] = v.x; w_lds[nn][(q * 4 + 1) * 4 + g] = v.y;
                    w_lds[nn][(q * 4 + 2) * 4 + g] = v.z; w_lds[nn][(q * 4 + 3) * 4 + g] = v.w;
                }
            }
            {
                int b = tid >> 3, nb = (tid & 7) * 8;
                const float4* ph = (const float4*)(out + ((size_t)(b * TT + (t - 1)) * IC + i) * NDIM + n0 + nb);
                float4 h0 = ph[0], h1 = ph[1];
                h_lds[nb + 0][b] = h0.x; h_lds[nb + 1][b] = h0.y; h_lds[nb + 2][b] = h0.z; h_lds[nb + 3][b] = h0.w;
                h_lds[nb + 4][b] = h1.x; h_lds[nb + 5][b] = h1.y; h_lds[nb + 6][b] = h1.z; h_lds[nb + 7][b] = h1.w;
            }
            __syncthreads();
            #pragma unroll 8
            for (int nn = 0; nn < NC; nn++) {
                float4 wv = *(const float4*)&w_lds[nn][kl * 4];
                float4 hv = *(const float4*)&h_lds[nn][bg * 4];
                acc[0][0] += hv.x * wv.x; acc[1][0] += hv.x * wv.y; acc[2][0] += hv.x * wv.z; acc[3][0] += hv.x * wv.w;
                acc[0][1] += hv.y * wv.x; acc[1][1] += hv.y * wv.y; acc[2][1] += hv.y * wv.z; acc[3][1] += hv.y * wv.w;
                acc[0][2] += hv.z * wv.x; acc[1][2] += hv.z * wv.y; acc[2][2] += hv.z * wv.z; acc[3][2] += hv.z * wv.w;
                acc[0][3] += hv.w * wv.x; acc[1][3] += hv.w * wv.y; acc[2][3] += hv.w * wv.z; acc[3][3] += hv.w * wv.w;
            }
        }
    }
    const float a_out = 0.990049834f;
    #pragma unroll
    for (int j = 0; j < 4; j++) {
        int b = bg * 4 + j;
        size_t sidx = ((size_t)b * IC + i) * NDIM + kg;
        float jg = tanhf(acc[0][j]), ig = sigf(acc[1][j]), fg = sigf(acc[2][j]), og = sigf(acc[3][j]);
        float alpha_m = expf(-7.8125e-5f * jg);
        float ro = expf(-1.5625e-4f * ig);
        float b_ad = ro * 0.1f + (1.0f - ro) * ig;
        float Bth = 0.04f + 1.8f * b_ad;
        float hprev = 0.0f, cprev = 0.0f;
        if (t > 0) { hprev = out[((size_t)(b * TT + (t - 1)) * IC + i) * NDIM + kg]; cprev = cfin[sidx]; }
        float mem = jg * alpha_m + (1.0f - alpha_m) * hprev - Bth * ig * 0.01f;
        float spike = (mem - Bth) > 0.0f ? 1.0f : 0.0f;
        float mem_o = mem * a_out + (1.0f - a_out) * spike + 0.08f;
        float cn = cprev * fg + ig * spike * mem_o;
        float hn = og * tanhf(cn);
        cfin[sidx] = cn;
        out[((size_t)(b * TT + t) * IC + i) * NDIM + kg] = hn;
        if (t == TT - 1) hfin[sidx] = hn;
    }
}

extern "C" void kernel_launch(void* const* d_in, const int* in_sizes, int n_in,
                              void* d_out, int out_size, void* d_ws, size_t ws_size,
                              hipStream_t stream) {
    const float* x   = (const float*)d_in[0];
    const float* Uj  = (const float*)d_in[1];
    const float* Ui_ = (const float*)d_in[2];
    const float* Uf  = (const float*)d_in[3];
    const float* Uo  = (const float*)d_in[4];
    const float* Wj  = (const float*)d_in[5];
    const float* Wi  = (const float*)d_in[6];
    const float* Wf  = (const float*)d_in[7];
    const float* Wo  = (const float*)d_in[8];
    const float* bj  = (const float*)d_in[9];
    const float* bi_ = (const float*)d_in[10];
    const float* bf_ = (const float*)d_in[11];
    const float* bo  = (const float*)d_in[12];
    float* out = (float*)d_out;

    if (ws_size >= WS_NEED) {
        static bool attr_set = false;
        if (!attr_set) {   // opt-in to 128 KiB dynamic LDS (host-side, not captured)
            (void)hipFuncSetAttribute((const void*)es_persist,
                                      hipFuncAttributeMaxDynamicSharedMemorySize, SMEM_BYTES);
            attr_set = true;
        }
        pack_w<<<dim3(2048), dim3(256), 0, stream>>>(Wj, Wi, Wf, Wo, (uint4*)d_ws);
        es_persist<<<dim3(256), dim3(256), SMEM_BYTES, stream>>>(
            x, Uj, Ui_, Uf, Uo, (const uint4*)d_ws, bj, bi_, bf_, bo, out);
    } else {
        for (int t = 0; t < TT; t++) {
            step_kernel_valu<<<dim3(IC, NDIM / KT), dim3(256), 0, stream>>>(
                t, x, Uj, Ui_, Uf, Uo, Wj, Wi, Wf, Wo, bj, bi_, bf_, bo, out);
        }
    }
}

// Round 8
// 699.319 us; speedup vs baseline: 5.5664x; 1.2576x over previous
//
#include <hip/hip_runtime.h>
#include <hip/hip_bf16.h>

typedef __hip_bfloat16 bf16;
typedef unsigned short ushort_t;
typedef __attribute__((ext_vector_type(8))) short short8;
typedef __attribute__((ext_vector_type(4))) float float4v;

#define BSZ 32
#define TT  128
#define IC  16
#define NDIM 512
#define WS_NEED ((size_t)4 * IC * NDIM * NDIM * 2)   // 33.55 MB bf16 packed weights
#define SMEM_BYTES 131072                            // 32 KiB h + slack to force 1 block/CU

// Per-(channel,tile) flag words: g_flag[i*64+kt] = latest published step+1.
// SINGLE WRITER per word; all accesses sc0 sc1 (MALL-coherent). Zeroed by pack_w.
__device__ __attribute__((aligned(256))) unsigned g_flag[IC * 64];
// bf16 h exchange buffer, double-buffered by step parity. Written/read ONLY with
// sc0 sc1 (never L2-cached -> no staleness possible). 1 MB static.
__device__ __attribute__((aligned(256))) ushort_t g_hx[2][IC][BSZ * NDIM];

__device__ __forceinline__ unsigned f2bfb(float f) {
    bf16 h = __float2bfloat16(f);
    return (unsigned)*reinterpret_cast<unsigned short*>(&h);
}
// fast transcendentals: v_exp + v_rcp (1 ulp each) — error ~1e-7, far below the
// 2^-15 bf16-h quantization floor that dominates absmax.
__device__ __forceinline__ float frcp(float x) { return __builtin_amdgcn_rcpf(x); }
__device__ __forceinline__ float ftanh(float x) {
    float cx = fminf(fmaxf(x, -9.0f), 9.0f);       // tanh(9) = 1 - 3e-8
    float e  = __expf(2.0f * cx);
    return 1.0f - 2.0f * frcp(e + 1.0f);
}
__device__ __forceinline__ float fsig(float x) {
    return frcp(1.0f + __expf(-x));
}
__device__ __forceinline__ float sigf(float v) { return 1.0f / (1.0f + expf(-v)); }

// ---------------- one-time weight pack: fp32 W -> bf16 MFMA B-fragments ----
// uint4 index = ((blk*16 + kstep)*64 + lane), blk = (g*IC + i)*32 + nt16
// lane frag elems j=0..7:  W_g[i][ kstep*32 + (lane>>4)*8 + j ][ nt16*16 + (lane&15) ]
__global__ void pack_w(const float* __restrict__ Wj, const float* __restrict__ Wi,
                       const float* __restrict__ Wf, const float* __restrict__ Wo,
                       uint4* __restrict__ wpk)
{
    __shared__ float tile[NDIM][17];
    const int blk  = blockIdx.x;
    if (blk == 0) {   // reset flags; visible via end-of-kernel writeback
        for (int k = threadIdx.x; k < IC * 64; k += 256) g_flag[k] = 0u;
    }
    const int nt16 = blk & 31;
    const int i    = (blk >> 5) & 15;
    const int g    = blk >> 9;
    const float* W = (g == 0) ? Wj : (g == 1) ? Wi : (g == 2) ? Wf : Wo;
    const float* base = W + (size_t)i * NDIM * NDIM + nt16 * 16;
    const int tid = threadIdx.x;

    #pragma unroll
    for (int r = 0; r < 2; r++) {
        int n = tid + r * 256;
        const float4* p = (const float4*)(base + (size_t)n * NDIM);
        float4 v0 = p[0], v1 = p[1], v2 = p[2], v3 = p[3];
        float* d = &tile[n][0];
        d[0]=v0.x; d[1]=v0.y; d[2]=v0.z; d[3]=v0.w;
        d[4]=v1.x; d[5]=v1.y; d[6]=v1.z; d[7]=v1.w;
        d[8]=v2.x; d[9]=v2.y; d[10]=v2.z; d[11]=v2.w;
        d[12]=v3.x; d[13]=v3.y; d[14]=v3.z; d[15]=v3.w;
    }
    __syncthreads();
    #pragma unroll
    for (int p = 0; p < 4; p++) {
        int f = p * 256 + tid;
        int kstep = f >> 6, L = f & 63;
        int quad = L >> 4, col = L & 15;
        int nr = kstep * 32 + quad * 8;
        unsigned u[4];
        #pragma unroll
        for (int w = 0; w < 4; w++) {
            unsigned lo = f2bfb(tile[nr + 2 * w][col]);
            unsigned hi = f2bfb(tile[nr + 2 * w + 1][col]);
            u[w] = lo | (hi << 16);
        }
        wpk[(size_t)blk * 1024 + (size_t)kstep * 64 + L] = make_uint4(u[0], u[1], u[2], u[3]);
    }
}

// ---------------- persistent all-timesteps kernel ----------------
// 256 blocks, 1 block/CU. Block = (channel i = bid&15, tile kt = bid>>4).
// Weights in REGISTERS all 128 steps. Cross-block h exchange: bf16 via g_hx
// (double-buffered), sc0 sc1 only. Single-writer flags; spin cap -> fail loud.
__launch_bounds__(256, 1)
__global__ void es_persist(
    const float* __restrict__ x,
    const float* __restrict__ Uj, const float* __restrict__ Ui,
    const float* __restrict__ Uf, const float* __restrict__ Uo,
    const uint4* __restrict__ wpk,
    const float* __restrict__ bj, const float* __restrict__ bi,
    const float* __restrict__ bfp, const float* __restrict__ bo,
    float* __restrict__ out)
{
    extern __shared__ unsigned char smem[];
    unsigned char* h_base = smem;              // 32 KiB: row b at b*1024 B, chunk c at ((c^(b&7))<<4)

    const int bid = blockIdx.x;
    const int i   = bid & 15;                  // channel
    const int kt  = bid >> 4;                  // 32-col tile
    const int tid = threadIdx.x;
    const int wid = tid >> 6, L = tid & 63;
    const int quad = L >> 4, c15 = L & 15;
    const int ntl  = wid & 1;                  // local 16-col tile
    const int nt16 = kt * 2 + ntl;
    const int Mh   = (wid >> 1) * 16;          // batch half

    float* hfin = out + (size_t)BSZ * TT * IC * NDIM;
    float* cfin = hfin + (size_t)BSZ * IC * NDIM;

    // ---- prologue: this wave's B-fragments -> REGISTERS (once, stays all 128 steps)
    const size_t gstride = (size_t)IC * 32 * 1024;                    // uint4s per gate
    const uint4* bbase = wpk + ((size_t)i * 32 + nt16) * 1024 + L;
    short8 bfr0[16], bfr1[16], bfr2[16], bfr3[16];
    #pragma unroll
    for (int ks = 0; ks < 16; ks++) bfr0[ks] = *(const short8*)(bbase + (size_t)ks * 64);
    #pragma unroll
    for (int ks = 0; ks < 16; ks++) bfr1[ks] = *(const short8*)(bbase + gstride + (size_t)ks * 64);
    #pragma unroll
    for (int ks = 0; ks < 16; ks++) bfr2[ks] = *(const short8*)(bbase + 2 * gstride + (size_t)ks * 64);
    #pragma unroll
    for (int ks = 0; ks < 16; ks++) bfr3[ks] = *(const short8*)(bbase + 3 * gstride + (size_t)ks * 64);

    // ---- loop-invariant per-lane scalars
    const int n = nt16 * 16 + c15;
    const size_t un = (size_t)i * NDIM + n;
    const float u0 = Uj[un], u1 = Ui[un], u2 = Uf[un], u3 = Uo[un];
    const float c0 = bj[un], c1 = bi[un], c2 = bfp[un], c3 = bo[un];
    const float a_out = 0.990049834f;          // exp(-0.01)
    const float onea  = 0.009950166f;          // 1 - exp(-0.01)

    float cc[4] = {0.f, 0.f, 0.f, 0.f};        // c-state in registers across all steps

    #pragma unroll 1
    for (int t = 0; t < TT; t++) {
        float4v acc0 = {0,0,0,0}, acc1 = {0,0,0,0}, acc2 = {0,0,0,0}, acc3 = {0,0,0,0};

        // x loads depend on no other block: issue before the wait
        float xv[4];
        #pragma unroll
        for (int r = 0; r < 4; r++)
            xv[r] = x[(size_t)((Mh + quad * 4 + r) * TT + t) * IC + i];

        if (t > 0) {
            // ---- per-wave detect: lanes 0-15 poll 16 single-writer flags (MALL).
            // Hot spin first (load latency dominates); sleep only if clearly behind.
            {
                const unsigned* fp = &g_flag[(i << 6) + (L & 15)];
                bool need = (L < 16);
                unsigned v = 0;
                int spins = 0;
                while (__ballot((int)need) != 0ull) {
                    if (need) {
                        asm volatile("global_load_dword %0, %1, off sc0 sc1\n\ts_waitcnt vmcnt(0)"
                                     : "=v"(v) : "v"(fp) : "memory");
                        if (v >= (unsigned)t) need = false;
                    }
                    if (need && spins > 8) __builtin_amdgcn_s_sleep(1);
                    if (++spins > 40000) break;   // fail loud (bad data), never hang
                }
            }

            // ---- gather h(t-1) as bf16: 8 coalesced sc0sc1 dwordx4 per thread
            // (1 KB contiguous per wave instr), no conversion needed.
            const ushort_t* gsrc = &g_hx[(t - 1) & 1][i][0];
            float4v hg[8];
            #pragma unroll
            for (int q = 0; q < 8; q++) {
                const ushort_t* s = gsrc + (size_t)(q * 4 + wid) * NDIM + L * 8;
                asm volatile("global_load_dwordx4 %0, %1, off sc0 sc1" : "=v"(hg[q]) : "v"(s));
            }
            asm volatile("s_waitcnt vmcnt(0)" ::: "memory");
            __builtin_amdgcn_sched_barrier(0);

            // ---- swizzled LDS write (b128, conflict-free permutation per row)
            #pragma unroll
            for (int q = 0; q < 8; q++) {
                int b = q * 4 + wid;
                *(float4v*)(h_base + b * 1024 + ((L ^ (b & 7)) << 4)) = hg[q];
            }
            __syncthreads();

            // ---- MFMA: A from swizzled h LDS, B resident in registers
            const int arow = Mh + c15;
            const unsigned char* aptr = h_base + arow * 1024;
            const int ax = arow & 7;
            #pragma unroll
            for (int ks = 0; ks < 16; ks++) {
                short8 a = *(const short8*)(aptr + (((ks * 4 + quad) ^ ax) << 4));
                acc0 = __builtin_amdgcn_mfma_f32_16x16x32_bf16(a, bfr0[ks], acc0, 0, 0, 0);
                acc1 = __builtin_amdgcn_mfma_f32_16x16x32_bf16(a, bfr1[ks], acc1, 0, 0, 0);
                acc2 = __builtin_amdgcn_mfma_f32_16x16x32_bf16(a, bfr2[ks], acc2, 0, 0, 0);
                acc3 = __builtin_amdgcn_mfma_f32_16x16x32_bf16(a, bfr3[ks], acc3, 0, 0, 0);
            }
        }

        // ---- epilogue: fast-math gates (v_exp/v_rcp), linearized tiny exps.
        // exp(x)=1+x for |x|<=1.6e-4 is exact to fp32 rounding (x^2/2 < half-ulp).
        ushort_t* gdst = &g_hx[t & 1][i][0];
        #pragma unroll
        for (int r = 0; r < 4; r++) {
            const int b = Mh + quad * 4 + r;    // C-layout row

            float jg = ftanh(acc0[r] + c0 + xv[r] * u0);
            float ig = fsig (acc1[r] + c1 + xv[r] * u1);
            float fg = fsig (acc2[r] + c2 + xv[r] * u2);
            float og = fsig (acc3[r] + c3 + xv[r] * u3);

            float am1 = 7.8125e-5f * jg;        // 1 - alpha_m (exact linearization)
            float s1  = 1.5625e-4f * ig;        // 1 - ro      (exact linearization)
            float b_ad = fmaf(s1, ig - 0.1f, 0.1f);
            float Bth  = fmaf(1.8f, b_ad, 0.04f);

            float hprev = 0.0f;
            if (t > 0)   // coeff am1 ~7.8e-5: bf16 h is free (same as verified path)
                hprev = __bfloat162float(*(const bf16*)(h_base + b * 1024
                            + (((n >> 3) ^ (b & 7)) << 4) + (n & 7) * 2));

            float mem   = fmaf(am1, hprev - jg, jg) - 0.01f * Bth * ig;
            float spike = (mem - Bth) > 0.0f ? 1.0f : 0.0f;
            float mem_o = mem * a_out + onea * spike + 0.08f;

            float cn = fmaf(cc[r], fg, ig * spike * mem_o);
            float hn = og * ftanh(cn);
            cc[r] = cn;

            // bf16 h for the exchange (MALL, write-through) — same rounding as the
            // verified LDS path, so numerics are bit-identical.
            ushort_t* gp = gdst + (size_t)b * NDIM + n;
            unsigned hb = f2bfb(hn);
            asm volatile("global_store_short %0, %1, off sc0 sc1" :: "v"(gp), "v"(hb) : "memory");
            // fp32 h for the harness output: plain cached store (no in-kernel reader)
            out[((size_t)(b * TT + t) * IC + i) * NDIM + n] = hn;
            if (t == TT - 1) {
                size_t sidx = ((size_t)b * IC + i) * NDIM + n;
                cfin[sidx] = cn;
                hfin[sidx] = hn;
            }
        }

        // ---- publish h(t): drain stores (MALL ack), join, set flag word
        if (t < TT - 1) {
            asm volatile("s_waitcnt vmcnt(0)" ::: "memory");
            __syncthreads();
            if (tid == 0) {
                unsigned tv = (unsigned)(t + 1);
                const unsigned* fp = &g_flag[(i << 6) + kt];
                asm volatile("global_store_dword %0, %1, off sc0 sc1" :: "v"(fp), "v"(tv) : "memory");
            }
        }
    }
}

// ---------------- fallback (proven R5 path, used only if ws too small) ----
#define KT 32
#define NC 64
__launch_bounds__(256)
__global__ void step_kernel_valu(int t,
    const float* __restrict__ x,
    const float* __restrict__ Uj, const float* __restrict__ Ui, const float* __restrict__ Uf, const float* __restrict__ Uo,
    const float* __restrict__ Wj, const float* __restrict__ Wi, const float* __restrict__ Wf, const float* __restrict__ Wo,
    const float* __restrict__ bj, const float* __restrict__ bi, const float* __restrict__ bfp, const float* __restrict__ bo,
    float* __restrict__ out)
{
    __shared__ float w_lds[NC][KT * 4 + 4];
    __shared__ float h_lds[NC][BSZ + 4];
    const int i = blockIdx.x, k0 = blockIdx.y * KT, tid = threadIdx.x;
    const int kl = tid & 31, bg = tid >> 5, kg = k0 + kl;
    float* hfin = out + (size_t)BSZ * TT * IC * NDIM;
    float* cfin = hfin + (size_t)BSZ * IC * NDIM;
    float acc[4][4];
    {
        size_t uidx = (size_t)i * NDIM + kg;
        float u0 = Uj[uidx], u1 = Ui[uidx], u2 = Uf[uidx], u3 = Uo[uidx];
        float c0 = bj[uidx], c1 = bi[uidx], c2 = bfp[uidx], c3 = bo[uidx];
        #pragma unroll
        for (int j = 0; j < 4; j++) {
            int b = bg * 4 + j;
            float xv = x[(size_t)(b * TT + t) * IC + i];
            acc[0][j] = c0 + xv * u0; acc[1][j] = c1 + xv * u1;
            acc[2][j] = c2 + xv * u2; acc[3][j] = c3 + xv * u3;
        }
    }
    if (t > 0) {
        for (int n0 = 0; n0 < NDIM; n0 += NC) {
            __syncthreads();
            {
                int g = tid >> 6, nn = tid & 63;
                const float* Wp = (g == 0) ? Wj : (g == 1) ? Wi : (g == 2) ? Wf : Wo;
                const float4* p = (const float4*)(Wp + ((size_t)i * NDIM + (size_t)(n0 + nn)) * NDIM + k0);
                #pragma unroll
                for (int q = 0; q < 8; q++) {
                    float4 v = p[q];
                    w_lds[nn][(q * 4 + 0) * 4 + g] = v.x; w_lds[nn][(q * 4 + 1) * 4 + g] = v.y;
                    w_lds[nn][(q * 4 + 2) * 4 + g] = v.z; w_lds[nn][(q * 4 + 3) * 4 + g] = v.w;
                }
            }
            {
                int b = tid >> 3, nb = (tid & 7) * 8;
                const float4* ph = (const float4*)(out + ((size_t)(b * TT + (t - 1)) * IC + i) * NDIM + n0 + nb);
                float4 h0 = ph[0], h1 = ph[1];
                h_lds[nb + 0][b] = h0.x; h_lds[nb + 1][b] = h0.y; h_lds[nb + 2][b] = h0.z; h_lds[nb + 3][b] = h0.w;
                h_lds[nb + 4][b] = h1.x; h_lds[nb + 5][b] = h1.y; h_lds[nb + 6][b] = h1.z; h_lds[nb + 7][b] = h1.w;
            }
            __syncthreads();
            #pragma unroll 8
            for (int nn = 0; nn < NC; nn++) {
                float4 wv = *(const float4*)&w_lds[nn][kl * 4];
                float4 hv = *(const float4*)&h_lds[nn][bg * 4];
                acc[0][0] += hv.x * wv.x; acc[1][0] += hv.x * wv.y; acc[2][0] += hv.x * wv.z; acc[3][0] += hv.x * wv.w;
                acc[0][1] += hv.y * wv.x; acc[1][1] += hv.y * wv.y; acc[2][1] += hv.y * wv.z; acc[3][1] += hv.y * wv.w;
                acc[0][2] += hv.z * wv.x; acc[1][2] += hv.z * wv.y; acc[2][2] += hv.z * wv.z; acc[3][2] += hv.z * wv.w;
                acc[0][3] += hv.w * wv.x; acc[1][3] += hv.w * wv.y; acc[2][3] += hv.w * wv.z; acc[3][3] += hv.w * wv.w;
            }
        }
    }
    const float a_out = 0.990049834f;
    #pragma unroll
    for (int j = 0; j < 4; j++) {
        int b = bg * 4 + j;
        size_t sidx = ((size_t)b * IC + i) * NDIM + kg;
        float jg = tanhf(acc[0][j]), ig = sigf(acc[1][j]), fg = sigf(acc[2][j]), og = sigf(acc[3][j]);
        float alpha_m = expf(-7.8125e-5f * jg);
        float ro = expf(-1.5625e-4f * ig);
        float b_ad = ro * 0.1f + (1.0f - ro) * ig;
        float Bth = 0.04f + 1.8f * b_ad;
        float hprev = 0.0f, cprev = 0.0f;
        if (t > 0) { hprev = out[((size_t)(b * TT + (t - 1)) * IC + i) * NDIM + kg]; cprev = cfin[sidx]; }
        float mem = jg * alpha_m + (1.0f - alpha_m) * hprev - Bth * ig * 0.01f;
        float spike = (mem - Bth) > 0.0f ? 1.0f : 0.0f;
        float mem_o = mem * a_out + (1.0f - a_out) * spike + 0.08f;
        float cn = cprev * fg + ig * spike * mem_o;
        float hn = og * tanhf(cn);
        cfin[sidx] = cn;
        out[((size_t)(b * TT + t) * IC + i) * NDIM + kg] = hn;
        if (t == TT - 1) hfin[sidx] = hn;
    }
}

extern "C" void kernel_launch(void* const* d_in, const int* in_sizes, int n_in,
                              void* d_out, int out_size, void* d_ws, size_t ws_size,
                              hipStream_t stream) {
    const float* x   = (const float*)d_in[0];
    const float* Uj  = (const float*)d_in[1];
    const float* Ui_ = (const float*)d_in[2];
    const float* Uf  = (const float*)d_in[3];
    const float* Uo  = (const float*)d_in[4];
    const float* Wj  = (const float*)d_in[5];
    const float* Wi  = (const float*)d_in[6];
    const float* Wf  = (const float*)d_in[7];
    const float* Wo  = (const float*)d_in[8];
    const float* bj  = (const float*)d_in[9];
    const float* bi_ = (const float*)d_in[10];
    const float* bf_ = (const float*)d_in[11];
    const float* bo  = (const float*)d_in[12];
    float* out = (float*)d_out;

    if (ws_size >= WS_NEED) {
        static bool attr_set = false;
        if (!attr_set) {   // opt-in to 128 KiB dynamic LDS (host-side, not captured)
            (void)hipFuncSetAttribute((const void*)es_persist,
                                      hipFuncAttributeMaxDynamicSharedMemorySize, SMEM_BYTES);
            attr_set = true;
        }
        pack_w<<<dim3(2048), dim3(256), 0, stream>>>(Wj, Wi, Wf, Wo, (uint4*)d_ws);
        es_persist<<<dim3(256), dim3(256), SMEM_BYTES, stream>>>(
            x, Uj, Ui_, Uf, Uo, (const uint4*)d_ws, bj, bi_, bf_, bo, out);
    } else {
        for (int t = 0; t < TT; t++) {
            step_kernel_valu<<<dim3(IC, NDIM / KT), dim3(256), 0, stream>>>(
                t, x, Uj, Ui_, Uf, Uo, Wj, Wi, Wf, Wo, bj, bi_, bf_, bo, out);
        }
    }
}